// Round 2
// baseline (18341.835 us; speedup 1.0000x reference)
//
#include <hip/hip_runtime.h>
#include <math.h>

#define BB 256
#define TT 128
#define DD 128
#define HH 1024
#define G4 4096
#define TOUT 127
#define OSZ (BB * TOUT * DD)
#define NKB 36                  // (128+1024)/32 K-blocks of the gates GEMM
#define ACTE (16 * NKB * 512)   // elems (u16) of one activation frag-blob: 294912

typedef __bf16 bf16x8 __attribute__((ext_vector_type(8)));
typedef float f32x4 __attribute__((ext_vector_type(4)));
typedef unsigned short u16;
typedef unsigned int u32;

__device__ inline u16 f2bf(float f) {
    union { float f; u32 u; } v; v.f = f;
    u32 r = v.u + 0x7FFFu + ((v.u >> 16) & 1u);
    return (u16)(r >> 16);
}
__device__ inline float fsig(float x)  { return __fdividef(1.0f, 1.0f + __expf(-x)); }
__device__ inline float ftanh(float x) { return __fdividef(2.0f, 1.0f + __expf(-2.0f * x)) - 1.0f; }

// async global->LDS, 16B per lane; LDS base must be wave-uniform (HW adds lane*16)
__device__ __forceinline__ void gload_lds16(const u16* g, u16* l) {
    __builtin_amdgcn_global_load_lds(
        (const __attribute__((address_space(1))) u32*)g,
        (__attribute__((address_space(3))) u32*)l, 16, 0, 0);
}

// 16-counter grid barrier; counters padded to 64B. target = gen*16.
__device__ __forceinline__ void gbar(u32* bars, u32 target) {
    __syncthreads();
    if (threadIdx.x == 0)
        __hip_atomic_fetch_add(&bars[(blockIdx.x & 15) << 4], 1u,
                               __ATOMIC_RELEASE, __HIP_MEMORY_SCOPE_AGENT);
    if (threadIdx.x < 16) {
        while (__hip_atomic_load(&bars[threadIdx.x << 4],
                                 __ATOMIC_ACQUIRE, __HIP_MEMORY_SCOPE_AGENT) < target)
            __builtin_amdgcn_s_sleep(2);
    }
    __syncthreads();
    __builtin_amdgcn_fence(__ATOMIC_ACQUIRE, "agent");
}

struct SArgs {
    u16 *acts, *actp;                       // 2 x ACTE each (double-buffered blobs)
    const u16 *wS, *wP, *fswb, *pfcb;       // frag-ordered weight blobs
    const float *bS, *bP, *fsb, *pfb, *x;
    float* out;
    u32* bars;
};

// Gates GEMM 256x4096, K=1152 (frag blobs) + fused LSTM cell epilogue.
// Block: 64m x 64n; 8 waves = 2(kg K-split) x 2(wm) x 2(wn); 18 K-iters/group,
// double-buffered LDS staging via global_load_lds, f32 LDS reduce of K-groups.
__device__ __forceinline__ void lstm_gemm(
    const u16* __restrict__ act, const u16* __restrict__ wb,
    const float* __restrict__ bias, float* cbuf /*LDS [64][16]*/,
    u16* __restrict__ hact, u16 (&stg)[2][2][2][4][64][8],
    int bid, int w, int lane, int kg, int wf, int wm, int wn)
{
    const int mb0 = (bid >> 6) << 2;   // first mblk (4 per block)
    const int nb0 = (bid & 63) << 2;   // first nblk
    const int kb0 = kg * 18;

    const u16* gA = act + ((((size_t)(mb0 + wf)) * NKB + kb0) * 64 + lane) * 8;
    const u16* gB = wb  + ((((size_t)(nb0 + wf)) * NKB + kb0) * 64 + lane) * 8;

    f32x4 acc[2][2] = {};

    gload_lds16(gA, &stg[kg][0][0][wf][0][0]);
    gload_lds16(gB, &stg[kg][0][1][wf][0][0]);
    asm volatile("s_waitcnt vmcnt(0)" ::: "memory");
    __syncthreads();

    int buf = 0;
    for (int it = 0; it < 18; ++it) {
        if (it + 1 < 18) {
            gload_lds16(gA + (it + 1) * 512, &stg[kg][buf ^ 1][0][wf][0][0]);
            gload_lds16(gB + (it + 1) * 512, &stg[kg][buf ^ 1][1][wf][0][0]);
        }
        bf16x8 a0 = *(const bf16x8*)&stg[kg][buf][0][2 * wm + 0][lane][0];
        bf16x8 a1 = *(const bf16x8*)&stg[kg][buf][0][2 * wm + 1][lane][0];
        bf16x8 b0 = *(const bf16x8*)&stg[kg][buf][1][2 * wn + 0][lane][0];
        bf16x8 b1 = *(const bf16x8*)&stg[kg][buf][1][2 * wn + 1][lane][0];
        acc[0][0] = __builtin_amdgcn_mfma_f32_16x16x32_bf16(a0, b0, acc[0][0], 0, 0, 0);
        acc[0][1] = __builtin_amdgcn_mfma_f32_16x16x32_bf16(a0, b1, acc[0][1], 0, 0, 0);
        acc[1][0] = __builtin_amdgcn_mfma_f32_16x16x32_bf16(a1, b0, acc[1][0], 0, 0, 0);
        acc[1][1] = __builtin_amdgcn_mfma_f32_16x16x32_bf16(a1, b1, acc[1][1], 0, 0, 0);
        asm volatile("s_waitcnt vmcnt(0)" ::: "memory");
        __syncthreads();
        buf ^= 1;
    }

    // reduce the two K-groups through LDS (reuse stg as f32 scratch)
    float* red = (float*)&stg[0][0][0][0][0][0];
#pragma unroll
    for (int mi = 0; mi < 2; ++mi)
#pragma unroll
    for (int ni = 0; ni < 2; ++ni)
        *(f32x4*)&red[((((w << 1) | mi) << 1 | ni) << 8) + (lane << 2)] = acc[mi][ni];
    __syncthreads();

    if (kg == 0) {
        const int col = lane & 15, row4 = (lane >> 4) << 2, g0 = lane & 3;
        const int m_base = (bid >> 6) << 6, n_base = (bid & 63) << 6;
#pragma unroll
        for (int mi = 0; mi < 2; ++mi)
#pragma unroll
        for (int ni = 0; ni < 2; ++ni) {
            f32x4 s0 = *(const f32x4*)&red[((((w << 1) | mi) << 1 | ni) << 8) + (lane << 2)];
            f32x4 s1 = *(const f32x4*)&red[(((((w + 4) << 1) | mi) << 1 | ni) << 8) + (lane << 2)];
            const int n = n_base + wn * 32 + ni * 16 + col;
            const float bv = bias[n];
#pragma unroll
            for (int rr = 0; rr < 4; ++rr) {
                float v = s0[rr] + s1[rr] + bv;
                float v1 = __shfl_xor(v, 1);
                float v2 = __shfl_xor(v, 2);
                float v3 = __shfl_xor(v, 3);
                if (g0 == 0) {  // lane holds gate i; v1=f, v2=g, v3=o
                    const int m = m_base + wm * 32 + mi * 16 + row4 + rr;
                    const int j = n >> 2;
                    const int ml = m - m_base, jl = j - (n_base >> 2);
                    float cp = cbuf[ml * 16 + jl];
                    float cy = cp * fsig(v1) + fsig(v) * ftanh(v2);
                    float hy = fsig(v3) * ftanh(cy);
                    cbuf[ml * 16 + jl] = cy;
                    hact[(((size_t)(m >> 4) * NKB + (4 + (j >> 5))) * 64 +
                          ((m & 15) + (((j >> 3) & 3) << 4))) * 8 + (j & 7)] = f2bf(hy);
                }
            }
        }
    }
}

__global__ __launch_bounds__(512, 2) void k_scan(SArgs A)
{
    __shared__ __align__(16) u16 stg[2][2][2][4][64][8];  // 32 KB staging/reduce union
    __shared__ float cst[2][64][16];                      // persistent c state (s,p)

    const int bid = blockIdx.x, tid = threadIdx.x;
    const int w = tid >> 6, lane = tid & 63;
    const int kg = w >> 2, wf = w & 3;
    const int wm = (w >> 1) & 1, wn = w & 1;

    for (int i = tid; i < 2 * 64 * 16; i += 512) ((float*)cst)[i] = 0.f;

    float* o_mask = A.out;
    float* o_x0   = A.out + 1 * (size_t)OSZ;
    float* o_x1   = A.out + 2 * (size_t)OSZ;
    float* o_reg  = A.out + 3 * (size_t)OSZ;
    float* o_mu   = A.out + 4 * (size_t)OSZ;
    float* o_prob = A.out + 5 * (size_t)OSZ;
    float* o_z    = A.out + 6 * (size_t)OSZ;

    u32 gen = 0;

    for (int t = 0; t < TOUT; ++t) {
        const u16* s_cur = A.acts + (size_t)(t & 1) * ACTE;
        u16*       s_nxt = A.acts + (size_t)((t + 1) & 1) * ACTE;
        u16*       p_cur = A.actp + (size_t)(t & 1) * ACTE;
        u16*       p_nxt = A.actp + (size_t)((t + 1) & 1) * ACTE;

        // ---- phase S: s-LSTM gates + cell; writes hs(t) into s_nxt ----
        lstm_gemm(s_cur, A.wS, A.bS, &cst[0][0][0], s_nxt, stg, bid, w, lane, kg, wf, wm, wn);
        gbar(A.bars, (++gen) * 16u);

        // ---- phase M: mu GEMM (256x128,K=1024) + mask/reg outputs + xin ----
        if (bid < 128) {
            const int bm = bid >> 3, bn = bid & 7;
            f32x4 acc = {};
#pragma unroll
            for (int i = 0; i < 4; ++i) {
                const int kb = (w << 2) + i;
                bf16x8 av = *(const bf16x8*)(s_nxt + (((size_t)bm * NKB + 4 + kb) * 64 + lane) * 8);
                bf16x8 bv = *(const bf16x8*)(A.fswb + (((size_t)bn * 32 + kb) * 64 + lane) * 8);
                acc = __builtin_amdgcn_mfma_f32_16x16x32_bf16(av, bv, acc, 0, 0, 0);
            }
            float* red = (float*)&stg[0][0][0][0][0][0];
            *(f32x4*)&red[((w * 64 + lane) << 2)] = acc;
            __syncthreads();
            if (tid < 256) {
                const int m16 = tid >> 4, d16 = tid & 15;
                const int rl = ((m16 >> 2) << 4) | d16, rr = m16 & 3;
                float v = 0.f;
#pragma unroll
                for (int ww = 0; ww < 8; ++ww) v += red[((ww * 64 + rl) << 2) + rr];
                const int m = (bm << 4) + m16, d = (bn << 4) + d16;
                float mu = v + A.fsb[d];
                float mask = fminf(fmaxf(mu + 0.5f, 0.f), 1.f);
                float reg = 0.5f * (1.0f + erff((mu + 0.5f) * 1.41421356237f));
                const size_t o = (size_t)m * (TOUT * DD) + (size_t)t * DD + d;
                o_mask[o] = mask; o_reg[o] = reg; o_mu[o] = mu; o_prob[o] = reg; o_z[o] = mu;
                float xv = A.x[(size_t)m * (TT * DD) + (size_t)(t + 1) * DD + d];
                p_cur[(((size_t)(m >> 4) * NKB + (d >> 5)) * 64 +
                       ((m & 15) + (((d >> 3) & 3) << 4))) * 8 + (d & 7)] = f2bf(mask * xv);
            }
        }
        gbar(A.bars, (++gen) * 16u);

        // ---- phase P: p-LSTM gates + cell; writes hp(t) into p_nxt ----
        lstm_gemm(p_cur, A.wP, A.bP, &cst[1][0][0], p_nxt, stg, bid, w, lane, kg, wf, wm, wn);
        gbar(A.bars, (++gen) * 16u);

        // ---- phase F: fc GEMM (256x256,K=1024) + xhat outputs + inp(t+1) ----
        if (bid < 128) {
            const int bm = bid >> 3, bn = bid & 7;
            f32x4 acc0 = {}, acc1 = {};
#pragma unroll
            for (int i = 0; i < 4; ++i) {
                const int kb = (w << 2) + i;
                bf16x8 av  = *(const bf16x8*)(p_nxt + (((size_t)bm * NKB + 4 + kb) * 64 + lane) * 8);
                bf16x8 bv0 = *(const bf16x8*)(A.pfcb + (((size_t)(2 * bn)     * 32 + kb) * 64 + lane) * 8);
                bf16x8 bv1 = *(const bf16x8*)(A.pfcb + (((size_t)(2 * bn + 1) * 32 + kb) * 64 + lane) * 8);
                acc0 = __builtin_amdgcn_mfma_f32_16x16x32_bf16(av, bv0, acc0, 0, 0, 0);
                acc1 = __builtin_amdgcn_mfma_f32_16x16x32_bf16(av, bv1, acc1, 0, 0, 0);
            }
            float* red = (float*)&stg[0][0][0][0][0][0];
            *(f32x4*)&red[(((w * 2 + 0) * 64 + lane) << 2)] = acc0;
            *(f32x4*)&red[(((w * 2 + 1) * 64 + lane) << 2)] = acc1;
            __syncthreads();
            {
                const int m16 = tid >> 5, n32 = tid & 31;
                const int ni = n32 >> 4, d16 = n32 & 15;
                const int rl = ((m16 >> 2) << 4) | d16, rr = m16 & 3;
                float v = 0.f;
#pragma unroll
                for (int ww = 0; ww < 8; ++ww) v += red[(((ww * 2 + ni) * 64 + rl) << 2) + rr];
                const int m = (bm << 4) + m16, n = (bn << 5) + n32;
                v += A.pfb[n];
                const size_t ob = (size_t)m * (TOUT * DD) + (size_t)t * DD;
                if (n < DD) {
                    o_x0[ob + n] = v;
                    float mk = o_mask[ob + n];
                    float xv = A.x[(size_t)m * (TT * DD) + (size_t)(t + 1) * DD + n];
                    s_nxt[(((size_t)(m >> 4) * NKB + (n >> 5)) * 64 +
                           ((m & 15) + (((n >> 3) & 3) << 4))) * 8 + (n & 7)] = f2bf(mk * xv + (1.f - mk) * v);
                } else {
                    o_x1[ob + (n - DD)] = v;
                }
            }
        }
        gbar(A.bars, (++gen) * 16u);
    }
}

// ---------------- setup kernels (once per call) ----------------

// gates weight blob: frag-ordered [256 nblk][36 kblk][64 lane][8], gate-interleaved rows
__global__ void k_wgates(const float* __restrict__ wx, const float* __restrict__ wh,
                         u16* __restrict__ blob) {
    int i = blockIdx.x * 256 + threadIdx.x;
    if (i >= 256 * NKB * 64) return;
    int lane = i & 63, cblk = (i >> 6) % NKB, rblk = (i >> 6) / NKB;
    int n = (rblk << 4) | (lane & 15);
    int c = (cblk << 5) + ((lane >> 4) << 3);
    int orow = ((n & 3) << 10) | (n >> 2);
    const float* s = (cblk < 4) ? (wx + (size_t)orow * DD + c)
                                : (wh + (size_t)orow * HH + (c - 128));
    u16* d = blob + (size_t)i * 8;
#pragma unroll
    for (int k = 0; k < 8; ++k) d[k] = f2bf(s[k]);
}

__global__ void k_wplain(const float* __restrict__ wsrc, u16* __restrict__ blob,
                         int nblk, int K) {
    int CB = K >> 5;
    int i = blockIdx.x * 256 + threadIdx.x;
    if (i >= nblk * CB * 64) return;
    int lane = i & 63, cblk = (i >> 6) % CB, rblk = (i >> 6) / CB;
    int r = (rblk << 4) | (lane & 15);
    int c = (cblk << 5) + ((lane >> 4) << 3);
    const float* s = wsrc + (size_t)r * K + c;
    u16* d = blob + (size_t)i * 8;
#pragma unroll
    for (int k = 0; k < 8; ++k) d[k] = f2bf(s[k]);
}

__global__ void k_bias2(const float* __restrict__ bx, const float* __restrict__ bh,
                        float* __restrict__ dst) {
    int r = blockIdx.x * 256 + threadIdx.x;
    if (r < G4) {
        int o = ((r & 3) << 10) | (r >> 2);
        dst[r] = bx[o] + bh[o];
    }
}

__global__ void k_zero(u16* acts, u16* actp, u32* bars) {
    size_t i = (size_t)blockIdx.x * 256 + threadIdx.x;
    if (i < 2 * (size_t)ACTE) { acts[i] = 0; actp[i] = 0; }
    if (i < 256) bars[i] = 0;
}

__global__ void k_fillx(const float* __restrict__ x, u16* __restrict__ acts) {
    int i = blockIdx.x * 256 + threadIdx.x;
    if (i >= BB * DD) return;
    int m = i >> 7, d = i & 127;
    acts[(((size_t)(m >> 4) * NKB + (d >> 5)) * 64 +
          ((m & 15) + (((d >> 3) & 3) << 4))) * 8 + (d & 7)] =
        f2bf(x[(size_t)m * (TT * DD) + d]);
}

extern "C" void kernel_launch(void* const* d_in, const int* in_sizes, int n_in,
                              void* d_out, int out_size, void* d_ws, size_t ws_size,
                              hipStream_t stream) {
    const float* x       = (const float*)d_in[0];
    const float* s_x2h_w = (const float*)d_in[1];
    const float* s_x2h_b = (const float*)d_in[2];
    const float* s_h2h_w = (const float*)d_in[3];
    const float* s_h2h_b = (const float*)d_in[4];
    const float* p_x2h_w = (const float*)d_in[5];
    const float* p_x2h_b = (const float*)d_in[6];
    const float* p_h2h_w = (const float*)d_in[7];
    const float* p_h2h_b = (const float*)d_in[8];
    const float* p_fc_w  = (const float*)d_in[9];
    const float* p_fc_b  = (const float*)d_in[10];
    const float* fs_w    = (const float*)d_in[11];
    const float* fs_b    = (const float*)d_in[12];

    char* ws = (char*)d_ws;
    size_t off = 0;
    auto alloc = [&](size_t bytes) { void* p = ws + off; off += (bytes + 255) & ~(size_t)255; return p; };
    u16*   wS   = (u16*)  alloc((size_t)G4 * 1152 * 2);
    u16*   wP   = (u16*)  alloc((size_t)G4 * 1152 * 2);
    u16*   fswb = (u16*)  alloc((size_t)8 * 32 * 512 * 2);
    u16*   pfcb = (u16*)  alloc((size_t)16 * 32 * 512 * 2);
    float* bS   = (float*)alloc((size_t)G4 * 4);
    float* bP   = (float*)alloc((size_t)G4 * 4);
    u16*   acts = (u16*)  alloc((size_t)2 * ACTE * 2);
    u16*   actp = (u16*)  alloc((size_t)2 * ACTE * 2);
    u32*   bars = (u32*)  alloc(1024);

    k_wgates<<<dim3(2304), 256, 0, stream>>>(s_x2h_w, s_h2h_w, wS);
    k_wgates<<<dim3(2304), 256, 0, stream>>>(p_x2h_w, p_h2h_w, wP);
    k_wplain<<<dim3(64),  256, 0, stream>>>(fs_w, fswb, 8, 1024);
    k_wplain<<<dim3(128), 256, 0, stream>>>(p_fc_w, pfcb, 16, 1024);
    k_bias2<<<dim3(16), 256, 0, stream>>>(s_x2h_b, s_h2h_b, bS);
    k_bias2<<<dim3(16), 256, 0, stream>>>(p_x2h_b, p_h2h_b, bP);
    k_zero<<<dim3(2304), 256, 0, stream>>>(acts, actp, bars);
    k_fillx<<<dim3(128), 256, 0, stream>>>(x, acts);

    SArgs sa;
    sa.acts = acts; sa.actp = actp;
    sa.wS = wS; sa.wP = wP; sa.fswb = fswb; sa.pfcb = pfcb;
    sa.bS = bS; sa.bP = bP; sa.fsb = fs_b; sa.pfb = p_fc_b; sa.x = x;
    sa.out = (float*)d_out; sa.bars = bars;

    void* kargs[] = { &sa };
    hipError_t e = hipLaunchCooperativeKernel((const void*)k_scan, dim3(256), dim3(512),
                                              kargs, 0, stream);
    if (e != hipSuccess) {
        // fallback: plain launch (grid == CU count; blocks co-resident in practice)
        k_scan<<<dim3(256), dim3(512), 0, stream>>>(sa);
    }
}

// Round 3
// 4684.878 us; speedup vs baseline: 3.9151x; 3.9151x over previous
//
#include <hip/hip_runtime.h>
#include <math.h>

#define BB 256
#define TT 128
#define DD 128
#define HH 1024
#define G4 4096
#define TOUT 127
#define OSZ (BB * TOUT * DD)
#define NKB 36                  // (128+1024)/32 K-blocks of the gates GEMM
#define ACTE (16 * NKB * 512)   // u16 elems of one activation frag-blob: 294912

typedef __bf16 bf16x8 __attribute__((ext_vector_type(8)));
typedef float f32x4 __attribute__((ext_vector_type(4)));
typedef unsigned short u16;
typedef unsigned int u32;

__device__ inline u16 f2bf(float f) {
    union { float f; u32 u; } v; v.f = f;
    u32 r = v.u + 0x7FFFu + ((v.u >> 16) & 1u);
    return (u16)(r >> 16);
}
__device__ inline float fsig(float x)  { return __fdividef(1.0f, 1.0f + __expf(-x)); }
__device__ inline float ftanh(float x) { return __fdividef(2.0f, 1.0f + __expf(-2.0f * x)) - 1.0f; }

// ---------------------------------------------------------------------------
// Gates GEMM 256x4096, K=1152 (frag blobs) + fused LSTM cell epilogue.
// Grid (64,8): 32m x 64n tile/block (2 blocks/CU). 4 waves: wn in {0,1} picks
// the n-half, kg in {0,1} splits K. LDS reduce of K-halves, epilogue on kg=0.
// Blob layout: [blk16][kblk][lane][8]: row=lane&15, k=kb*32+(lane>>4)*8+e.
// ---------------------------------------------------------------------------
__global__ __launch_bounds__(256) void k_lstm(
    const u16* __restrict__ act, const u16* __restrict__ wb,
    const float* __restrict__ bias, float* __restrict__ c, u16* __restrict__ hact)
{
    const int tid = threadIdx.x, lane = tid & 63, w = tid >> 6;
    const int wn = w & 1, kg = w >> 1;
    const int mb = blockIdx.y * 2;
    const int nb = blockIdx.x * 4 + wn * 2;

    const u16* a0 = act + (((size_t)(mb + 0) * NKB + kg * 18) * 64 + lane) * 8;
    const u16* a1 = act + (((size_t)(mb + 1) * NKB + kg * 18) * 64 + lane) * 8;
    const u16* b0 = wb  + (((size_t)(nb + 0) * NKB + kg * 18) * 64 + lane) * 8;
    const u16* b1 = wb  + (((size_t)(nb + 1) * NKB + kg * 18) * 64 + lane) * 8;

    f32x4 acc[2][2] = {};
#pragma unroll 6
    for (int it = 0; it < 18; ++it) {
        bf16x8 av0 = *(const bf16x8*)(a0 + it * 512);
        bf16x8 av1 = *(const bf16x8*)(a1 + it * 512);
        bf16x8 bv0 = *(const bf16x8*)(b0 + it * 512);
        bf16x8 bv1 = *(const bf16x8*)(b1 + it * 512);
        acc[0][0] = __builtin_amdgcn_mfma_f32_16x16x32_bf16(av0, bv0, acc[0][0], 0, 0, 0);
        acc[0][1] = __builtin_amdgcn_mfma_f32_16x16x32_bf16(av0, bv1, acc[0][1], 0, 0, 0);
        acc[1][0] = __builtin_amdgcn_mfma_f32_16x16x32_bf16(av1, bv0, acc[1][0], 0, 0, 0);
        acc[1][1] = __builtin_amdgcn_mfma_f32_16x16x32_bf16(av1, bv1, acc[1][1], 0, 0, 0);
    }

    __shared__ __align__(16) float red[2][2][2][64][4];  // [wn][mi][ni][lane][4] = 8KB
    if (kg == 1) {
#pragma unroll
        for (int mi = 0; mi < 2; ++mi)
#pragma unroll
        for (int ni = 0; ni < 2; ++ni)
            *(f32x4*)&red[wn][mi][ni][lane][0] = acc[mi][ni];
    }
    __syncthreads();
    if (kg == 0) {
        const int col = lane & 15, row4 = (lane >> 4) << 2, g0 = lane & 3;
        const int m_base = blockIdx.y * 32;
        const int n_base = blockIdx.x * 64 + wn * 32;
#pragma unroll
        for (int mi = 0; mi < 2; ++mi)
#pragma unroll
        for (int ni = 0; ni < 2; ++ni) {
            f32x4 s1 = *(const f32x4*)&red[wn][mi][ni][lane][0];
            const int n = n_base + ni * 16 + col;
            const float bv = bias[n];
#pragma unroll
            for (int rr = 0; rr < 4; ++rr) {
                float v = acc[mi][ni][rr] + s1[rr] + bv;
                float v1 = __shfl_xor(v, 1);
                float v2 = __shfl_xor(v, 2);
                float v3 = __shfl_xor(v, 3);
                if (g0 == 0) {  // lane holds gate i; v1=f, v2=g, v3=o
                    const int m = m_base + mi * 16 + row4 + rr;
                    const int j = n >> 2;
                    float cp = c[m * HH + j];
                    float cy = cp * fsig(v1) + fsig(v) * ftanh(v2);
                    float hy = fsig(v3) * ftanh(cy);
                    c[m * HH + j] = cy;
                    hact[(((size_t)(m >> 4) * NKB + (4 + (j >> 5))) * 64 +
                          ((m & 15) + (((j >> 3) & 3) << 4))) * 8 + (j & 7)] = f2bf(hy);
                }
            }
        }
    }
}

// ---------------------------------------------------------------------------
// mu = hs @ fs_w^T + fs_b (256x128, K=1024). Grid (8,16): 16x16 tile/block,
// 8 waves K-split, LDS reduce. Epilogue: mask/reg/mu/prob/z outputs + xin.
// ---------------------------------------------------------------------------
__global__ __launch_bounds__(512) void k_mu(
    const u16* __restrict__ h, const u16* __restrict__ W, const float* __restrict__ bias,
    const float* __restrict__ x, int t,
    float* __restrict__ o_mask, float* __restrict__ o_reg, float* __restrict__ o_mu,
    float* __restrict__ o_prob, float* __restrict__ o_z, u16* __restrict__ xin)
{
    const int tid = threadIdx.x, lane = tid & 63, w = tid >> 6;
    const int bn = blockIdx.x, bm = blockIdx.y;
    __shared__ __align__(16) float red[8 * 64 * 4];

    f32x4 acc = {};
#pragma unroll
    for (int i = 0; i < 4; ++i) {
        const int kb = (w << 2) + i;
        bf16x8 av = *(const bf16x8*)(h + (((size_t)bm * NKB + 4 + kb) * 64 + lane) * 8);
        bf16x8 bv = *(const bf16x8*)(W + (((size_t)bn * 32 + kb) * 64 + lane) * 8);
        acc = __builtin_amdgcn_mfma_f32_16x16x32_bf16(av, bv, acc, 0, 0, 0);
    }
    *(f32x4*)&red[(w * 64 + lane) << 2] = acc;
    __syncthreads();
    if (tid < 256) {
        const int m16 = tid >> 4, d16 = tid & 15;
        const int rl = ((m16 >> 2) << 4) | d16, rr = m16 & 3;
        float v = 0.f;
#pragma unroll
        for (int ww = 0; ww < 8; ++ww) v += red[((ww * 64 + rl) << 2) + rr];
        const int m = (bm << 4) + m16, d = (bn << 4) + d16;
        float mu = v + bias[d];
        float mask = fminf(fmaxf(mu + 0.5f, 0.f), 1.f);
        float reg = 0.5f * (1.0f + erff((mu + 0.5f) * 1.41421356237f));
        const size_t o = (size_t)m * (TOUT * DD) + (size_t)t * DD + d;
        o_mask[o] = mask; o_reg[o] = reg; o_mu[o] = mu; o_prob[o] = reg; o_z[o] = mu;
        float xv = x[(size_t)m * (TT * DD) + (size_t)(t + 1) * DD + d];
        xin[(((size_t)(m >> 4) * NKB + (d >> 5)) * 64 +
             ((m & 15) + (((d >> 3) & 3) << 4))) * 8 + (d & 7)] = f2bf(mask * xv);
    }
}

// ---------------------------------------------------------------------------
// xhat = hp @ p_fc_w^T + b (256x256, K=1024). Grid (16,16): 16x16 tile/block,
// 8 waves K-split, LDS reduce. Epilogue: xhat0/xhat1 + next-step s-input.
// ---------------------------------------------------------------------------
__global__ __launch_bounds__(512) void k_fc(
    const u16* __restrict__ h2, const u16* __restrict__ W, const float* __restrict__ bias,
    const float* __restrict__ x, int t, const float* __restrict__ o_mask,
    float* __restrict__ o_x0, float* __restrict__ o_x1, u16* __restrict__ inp_next)
{
    const int tid = threadIdx.x, lane = tid & 63, w = tid >> 6;
    const int bn = blockIdx.x, bm = blockIdx.y;
    __shared__ __align__(16) float red[8 * 64 * 4];

    f32x4 acc = {};
#pragma unroll
    for (int i = 0; i < 4; ++i) {
        const int kb = (w << 2) + i;
        bf16x8 av = *(const bf16x8*)(h2 + (((size_t)bm * NKB + 4 + kb) * 64 + lane) * 8);
        bf16x8 bv = *(const bf16x8*)(W + (((size_t)bn * 32 + kb) * 64 + lane) * 8);
        acc = __builtin_amdgcn_mfma_f32_16x16x32_bf16(av, bv, acc, 0, 0, 0);
    }
    *(f32x4*)&red[(w * 64 + lane) << 2] = acc;
    __syncthreads();
    if (tid < 256) {
        const int m16 = tid >> 4, d16 = tid & 15;
        const int rl = ((m16 >> 2) << 4) | d16, rr = m16 & 3;
        float v = 0.f;
#pragma unroll
        for (int ww = 0; ww < 8; ++ww) v += red[((ww * 64 + rl) << 2) + rr];
        const int m = (bm << 4) + m16, n = (bn << 4) + d16;
        v += bias[n];
        const size_t ob = (size_t)m * (TOUT * DD) + (size_t)t * DD;
        if (n < DD) {
            o_x0[ob + n] = v;
            float mk = o_mask[ob + n];
            float xv = x[(size_t)m * (TT * DD) + (size_t)(t + 1) * DD + n];
            inp_next[(((size_t)(m >> 4) * NKB + (n >> 5)) * 64 +
                      ((m & 15) + (((n >> 3) & 3) << 4))) * 8 + (n & 7)] =
                f2bf(mk * xv + (1.f - mk) * v);
        } else {
            o_x1[ob + (n - DD)] = v;
        }
    }
}

// ---------------- setup kernels (once per call) ----------------

// gates weight blob: frag-ordered [256 nblk][36 kblk][64 lane][8], gate-interleaved rows
__global__ void k_wgates(const float* __restrict__ wx, const float* __restrict__ wh,
                         u16* __restrict__ blob) {
    int i = blockIdx.x * 256 + threadIdx.x;
    if (i >= 256 * NKB * 64) return;
    int lane = i & 63, cblk = (i >> 6) % NKB, rblk = (i >> 6) / NKB;
    int n = (rblk << 4) | (lane & 15);
    int c = (cblk << 5) + ((lane >> 4) << 3);
    int orow = ((n & 3) << 10) | (n >> 2);
    const float* s = (cblk < 4) ? (wx + (size_t)orow * DD + c)
                                : (wh + (size_t)orow * HH + (c - 128));
    u16* d = blob + (size_t)i * 8;
#pragma unroll
    for (int k = 0; k < 8; ++k) d[k] = f2bf(s[k]);
}

__global__ void k_wplain(const float* __restrict__ wsrc, u16* __restrict__ blob,
                         int nblk, int K) {
    int CB = K >> 5;
    int i = blockIdx.x * 256 + threadIdx.x;
    if (i >= nblk * CB * 64) return;
    int lane = i & 63, cblk = (i >> 6) % CB, rblk = (i >> 6) / CB;
    int r = (rblk << 4) | (lane & 15);
    int c = (cblk << 5) + ((lane >> 4) << 3);
    const float* s = wsrc + (size_t)r * K + c;
    u16* d = blob + (size_t)i * 8;
#pragma unroll
    for (int k = 0; k < 8; ++k) d[k] = f2bf(s[k]);
}

__global__ void k_bias2(const float* __restrict__ bx, const float* __restrict__ bh,
                        float* __restrict__ dst) {
    int r = blockIdx.x * 256 + threadIdx.x;
    if (r < G4) {
        int o = ((r & 3) << 10) | (r >> 2);
        dst[r] = bx[o] + bh[o];
    }
}

__global__ void k_zero(u16* acts, u16* actp, float* cs, float* cp) {
    size_t i = (size_t)blockIdx.x * 256 + threadIdx.x;
    if (i < 2 * (size_t)ACTE) { acts[i] = 0; actp[i] = 0; }
    if (i < (size_t)BB * HH) { cs[i] = 0.f; cp[i] = 0.f; }
}

__global__ void k_fillx(const float* __restrict__ x, u16* __restrict__ acts) {
    int i = blockIdx.x * 256 + threadIdx.x;
    if (i >= BB * DD) return;
    int m = i >> 7, d = i & 127;
    acts[(((size_t)(m >> 4) * NKB + (d >> 5)) * 64 +
          ((m & 15) + (((d >> 3) & 3) << 4))) * 8 + (d & 7)] =
        f2bf(x[(size_t)m * (TT * DD) + d]);
}

extern "C" void kernel_launch(void* const* d_in, const int* in_sizes, int n_in,
                              void* d_out, int out_size, void* d_ws, size_t ws_size,
                              hipStream_t stream) {
    const float* x       = (const float*)d_in[0];
    const float* s_x2h_w = (const float*)d_in[1];
    const float* s_x2h_b = (const float*)d_in[2];
    const float* s_h2h_w = (const float*)d_in[3];
    const float* s_h2h_b = (const float*)d_in[4];
    const float* p_x2h_w = (const float*)d_in[5];
    const float* p_x2h_b = (const float*)d_in[6];
    const float* p_h2h_w = (const float*)d_in[7];
    const float* p_h2h_b = (const float*)d_in[8];
    const float* p_fc_w  = (const float*)d_in[9];
    const float* p_fc_b  = (const float*)d_in[10];
    const float* fs_w    = (const float*)d_in[11];
    const float* fs_b    = (const float*)d_in[12];

    float* out = (float*)d_out;
    float* o_mask = out + 0 * (size_t)OSZ;
    float* o_x0   = out + 1 * (size_t)OSZ;
    float* o_x1   = out + 2 * (size_t)OSZ;
    float* o_reg  = out + 3 * (size_t)OSZ;
    float* o_mu   = out + 4 * (size_t)OSZ;
    float* o_prob = out + 5 * (size_t)OSZ;
    float* o_z    = out + 6 * (size_t)OSZ;

    char* ws = (char*)d_ws;
    size_t off = 0;
    auto alloc = [&](size_t bytes) { void* p = ws + off; off += (bytes + 255) & ~(size_t)255; return p; };
    u16*   wS   = (u16*)  alloc((size_t)G4 * 1152 * 2);
    u16*   wP   = (u16*)  alloc((size_t)G4 * 1152 * 2);
    u16*   fswb = (u16*)  alloc((size_t)8 * 32 * 512 * 2);
    u16*   pfcb = (u16*)  alloc((size_t)16 * 32 * 512 * 2);
    float* bS   = (float*)alloc((size_t)G4 * 4);
    float* bP   = (float*)alloc((size_t)G4 * 4);
    u16*   acts = (u16*)  alloc((size_t)2 * ACTE * 2);
    u16*   actp = (u16*)  alloc((size_t)2 * ACTE * 2);
    float* cs   = (float*)alloc((size_t)BB * HH * 4);
    float* cp   = (float*)alloc((size_t)BB * HH * 4);

    k_wgates<<<dim3(2304), 256, 0, stream>>>(s_x2h_w, s_h2h_w, wS);
    k_wgates<<<dim3(2304), 256, 0, stream>>>(p_x2h_w, p_h2h_w, wP);
    k_wplain<<<dim3(64),  256, 0, stream>>>(fs_w, fswb, 8, 1024);
    k_wplain<<<dim3(128), 256, 0, stream>>>(p_fc_w, pfcb, 16, 1024);
    k_bias2<<<dim3(16), 256, 0, stream>>>(s_x2h_b, s_h2h_b, bS);
    k_bias2<<<dim3(16), 256, 0, stream>>>(p_x2h_b, p_h2h_b, bP);
    k_zero<<<dim3(2304), 256, 0, stream>>>(acts, actp, cs, cp);
    k_fillx<<<dim3(128), 256, 0, stream>>>(x, acts);

    for (int t = 0; t < TOUT; ++t) {
        const u16* s_cur = acts + (size_t)(t & 1) * ACTE;
        u16*       s_nxt = acts + (size_t)((t + 1) & 1) * ACTE;
        u16*       p_cur = actp + (size_t)(t & 1) * ACTE;
        u16*       p_nxt = actp + (size_t)((t + 1) & 1) * ACTE;

        k_lstm<<<dim3(64, 8), 256, 0, stream>>>(s_cur, wS, bS, cs, s_nxt);
        k_mu<<<dim3(8, 16), 512, 0, stream>>>(s_nxt, fswb, fs_b, x, t,
                                              o_mask, o_reg, o_mu, o_prob, o_z, p_cur);
        k_lstm<<<dim3(64, 8), 256, 0, stream>>>(p_cur, wP, bP, cp, p_nxt);
        k_fc<<<dim3(16, 16), 512, 0, stream>>>(p_nxt, pfcb, p_fc_b, x, t, o_mask,
                                               o_x0, o_x1, s_nxt);
    }
}